// Round 4
// baseline (78.401 us; speedup 1.0000x reference)
//
#include <hip/hip_runtime.h>
#include <cstddef>
#include <stdint.h>

// Problem constants: B=8, Tx=Ty=E=D=256
#define NB 8
#define TX 256
#define TY 256
#define NE 256

// 2*log2(e): tanh(t) = 1 - 2*rcp(1+exp2(CSC*t)); the constant 1-term cancels in
// softmax, so score s = -2 * sum_e v[e]*rcp(1+exp2(ws'[e][x]+uh'[y][e]))
#define CSC 2.8853900817779268f

// ---------------- prep: WsT[b][e][x] and Uh[b][y][e], both pre-scaled by CSC ----
// Grid 512 x (64,8). blk<256 -> Ws tiles (8 x-rows), blk>=256 -> Uh tiles (8 y-rows).
__global__ __launch_bounds__(512) void prep_kernel(
    const float* __restrict__ enc, const float* __restrict__ dec,
    const float* __restrict__ Wa, const float* __restrict__ Ua,
    float* __restrict__ WsT, float* __restrict__ Uh)
{
    const int tx = threadIdx.x;           // 0..63
    const int ty = threadIdx.y;           // 0..7
    const int tid = ty * 64 + tx;
    int blk = blockIdx.x;
    const bool isU = blk >= 256;
    if (isU) blk -= 256;
    const int b  = blk >> 5;              // 0..7
    const int r0 = (blk & 31) * 8;        // 8 rows per block

    __shared__ float rowsL[8 * NE];       // 8 KB input rows
    __shared__ float tL[8][260];          // transpose buffer (Ws only), padded

    const float* src = (isU ? dec : enc) + ((size_t)b * 256 + r0) * NE;
    ((float4*)rowsL)[tid] = ((const float4*)src)[tid];   // 2048 floats
    __syncthreads();

    const float* M = isU ? Ua : Wa;
    const int e0 = tx * 4;
    float4 acc = make_float4(0.f, 0.f, 0.f, 0.f);
    const float* rrow = rowsL + ty * NE;
    #pragma unroll 4
    for (int k = 0; k < NE; ++k) {
        const float4 mw = *(const float4*)(M + (size_t)k * NE + e0);
        const float a = rrow[k];
        acc.x = __builtin_fmaf(a, mw.x, acc.x);
        acc.y = __builtin_fmaf(a, mw.y, acc.y);
        acc.z = __builtin_fmaf(a, mw.z, acc.z);
        acc.w = __builtin_fmaf(a, mw.w, acc.w);
    }
    acc.x *= CSC; acc.y *= CSC; acc.z *= CSC; acc.w *= CSC;

    if (isU) {
        *(float4*)(Uh + ((size_t)b * TY + r0 + ty) * NE + e0) = acc;
    } else {
        *(float4*)&tL[ty][e0] = acc;
        __syncthreads();
        // coalesced transposed store: thread -> (e = tid>>1, 4 x's)
        const int e    = tid >> 1;
        const int half = (tid & 1) * 4;
        float4 o;
        o.x = tL[half + 0][e];
        o.y = tL[half + 1][e];
        o.z = tL[half + 2][e];
        o.w = tL[half + 3][e];
        *(float4*)(WsT + (size_t)b * NE * TX + (size_t)e * TX + r0 + half) = o;
    }
}

// ---------------- attn: scores -> softmax -> context ----------------
// Grid 512 = (b, y-tile of 4). Block (64,8) = 8 waves.
// Wave (yl = w>>1, eh = w&1): score partial for y = y0+yl over e-half eh.
// Lane tx owns x-quad [4tx, 4tx+4): reads a full coalesced WsT row per e.
// Softmax: wave-local shfl after cross-eh LDS combine.
// Context: wave (yl, xh = w&1): x-half, lane owns e-quad 4tx; combine 2 halves.
__global__ __launch_bounds__(512) void attn_kernel(
    const float* __restrict__ enc, const float* __restrict__ WsT,
    const float* __restrict__ Uh, const float* __restrict__ Va,
    float* __restrict__ c_out, float* __restrict__ e_out)
{
    const int tx = threadIdx.x;            // 0..63
    const int w  = threadIdx.y;            // 0..7
    const int tid = w * 64 + tx;
    const int yl = w >> 1;                 // 0..3
    const int eh = w & 1;                  // 0..1 (e-half in score, x-half in ctx)
    const int b  = blockIdx.x >> 6;        // 0..7
    const int y0 = (blockIdx.x & 63) * 4;
    const int y  = y0 + yl;

    __shared__ float2 uvL[4][NE];          // 8 KB: (uh'[y][e], v[e])
    __shared__ float4 accL[2][4][64];      // 8 KB: partial combine
    __shared__ float  pL[4][TX];           // 4 KB: softmax probs

    // stage (uh, v) pairs for the 4 y's
    #pragma unroll
    for (int i = tid; i < 4 * NE; i += 512) {
        const int yy = i >> 8;
        const int e  = i & 255;
        uvL[yy][e] = make_float2(Uh[((size_t)b * TY + y0 + yy) * NE + e], Va[e]);
    }
    __syncthreads();

    // ---- score: acc4 over x-quad, e in [eh*128, eh*128+128) ----
    const float* wp = WsT + (size_t)b * NE * TX + (size_t)eh * 128 * TX + tx * 4;
    const float2* uvy = &uvL[yl][eh * 128];
    float4 acc = make_float4(0.f, 0.f, 0.f, 0.f);
    #pragma unroll 4
    for (int e = 0; e < 128; ++e) {
        const float4 ws = *(const float4*)(wp + (size_t)e * TX);
        const float2 uv = uvy[e];
        const float r0 = __builtin_amdgcn_rcpf(1.f + __builtin_amdgcn_exp2f(ws.x + uv.x));
        const float r1 = __builtin_amdgcn_rcpf(1.f + __builtin_amdgcn_exp2f(ws.y + uv.x));
        const float r2 = __builtin_amdgcn_rcpf(1.f + __builtin_amdgcn_exp2f(ws.z + uv.x));
        const float r3 = __builtin_amdgcn_rcpf(1.f + __builtin_amdgcn_exp2f(ws.w + uv.x));
        acc.x = __builtin_fmaf(uv.y, r0, acc.x);
        acc.y = __builtin_fmaf(uv.y, r1, acc.y);
        acc.z = __builtin_fmaf(uv.y, r2, acc.z);
        acc.w = __builtin_fmaf(uv.y, r3, acc.w);
    }
    accL[eh][yl][tx] = acc;
    __syncthreads();

    // ---- wave-local softmax over x (both eh waves compute; eh==0 stores) ----
    const float4 a0 = accL[0][yl][tx];
    const float4 a1 = accL[1][yl][tx];
    float4 s;
    s.x = -2.f * (a0.x + a1.x);
    s.y = -2.f * (a0.y + a1.y);
    s.z = -2.f * (a0.z + a1.z);
    s.w = -2.f * (a0.w + a1.w);

    float m = fmaxf(fmaxf(s.x, s.y), fmaxf(s.z, s.w));
    #pragma unroll
    for (int off = 32; off; off >>= 1) m = fmaxf(m, __shfl_xor(m, off));
    float4 p;
    p.x = __expf(s.x - m);
    p.y = __expf(s.y - m);
    p.z = __expf(s.z - m);
    p.w = __expf(s.w - m);
    float sum = (p.x + p.y) + (p.z + p.w);
    #pragma unroll
    for (int off = 32; off; off >>= 1) sum += __shfl_xor(sum, off);
    const float inv = __builtin_amdgcn_rcpf(sum);
    p.x *= inv; p.y *= inv; p.z *= inv; p.w *= inv;

    if (eh == 0) {
        *(float4*)(e_out + ((size_t)b * TY + y) * TX + tx * 4) = p;
        *(float4*)&pL[yl][tx * 4] = p;
    }
    __syncthreads();

    // ---- context: c[y][e] = sum_x p[y][x]*enc[b][x][e]; wave takes x-half ----
    const int xh = eh;
    const float* ep = enc + (size_t)b * TX * NE + (size_t)xh * 128 * NE + tx * 4;
    const float* prow = &pL[yl][xh * 128];
    float4 cacc = make_float4(0.f, 0.f, 0.f, 0.f);
    #pragma unroll 4
    for (int x = 0; x < 128; ++x) {
        const float4 ev = *(const float4*)(ep + (size_t)x * NE);
        const float pv = prow[x];
        cacc.x = __builtin_fmaf(pv, ev.x, cacc.x);
        cacc.y = __builtin_fmaf(pv, ev.y, cacc.y);
        cacc.z = __builtin_fmaf(pv, ev.z, cacc.z);
        cacc.w = __builtin_fmaf(pv, ev.w, cacc.w);
    }
    accL[xh][yl][tx] = cacc;
    __syncthreads();
    if (xh == 0) {
        const float4 c0 = accL[0][yl][tx];
        const float4 c1 = accL[1][yl][tx];
        float4 cs;
        cs.x = c0.x + c1.x;
        cs.y = c0.y + c1.y;
        cs.z = c0.z + c1.z;
        cs.w = c0.w + c1.w;
        *(float4*)(c_out + ((size_t)b * TY + y) * NE + tx * 4) = cs;
    }
}

extern "C" void kernel_launch(void* const* d_in, const int* in_sizes, int n_in,
                              void* d_out, int out_size, void* d_ws, size_t ws_size,
                              hipStream_t stream) {
    const float* enc = (const float*)d_in[0];   // [B,Tx,E]
    const float* dec = (const float*)d_in[1];   // [B,Ty,D]
    const float* Wa  = (const float*)d_in[2];   // [E,E]
    const float* Ua  = (const float*)d_in[3];   // [D,E]
    const float* Va  = (const float*)d_in[4];   // [E,1]

    float* c_out = (float*)d_out;                               // [B,Ty,E]
    float* e_out = (float*)d_out + (size_t)NB * TY * NE;        // [B,Ty,Tx]

    float* WsT = (float*)d_ws;                                  // [B][E][Tx]
    float* Uh  = (float*)d_ws + (size_t)NB * NE * TX;           // [B][Ty][E]

    prep_kernel<<<512, dim3(64, 8), 0, stream>>>(enc, dec, Wa, Ua, WsT, Uh);
    attn_kernel<<<512, dim3(64, 8), 0, stream>>>(enc, WsT, Uh, Va, c_out, e_out);
}

// Round 5
// 72.871 us; speedup vs baseline: 1.0759x; 1.0759x over previous
//
#include <hip/hip_runtime.h>
#include <cstddef>
#include <stdint.h>

// Problem constants: B=8, Tx=Ty=E=D=256
#define NB 8
#define TX 256
#define TY 256
#define NE 256

// 2*log2(e): tanh(t) = 1 - 2*rcp(1+exp2(CSC*t)); the constant 1-term cancels in
// softmax, so score s = -2 * sum_e v[e]*rcp(1+exp2(ws'[e][x]+uh'[y][e]))
#define CSC 2.8853900817779268f

__device__ __forceinline__ void gload_lds16(const float* g, float* l) {
    __builtin_amdgcn_global_load_lds(
        (const __attribute__((address_space(1))) void*)g,
        (__attribute__((address_space(3))) void*)l,
        16, 0, 0);
}

// stage one 4096-float (16 KB) chunk: 512 threads x 2 x 16B
__device__ __forceinline__ void stage_chunk(const float* g, float* l, int tid, int w) {
    gload_lds16(g + tid * 4,        l + w * 256);          // floats [0,2048)
    gload_lds16(g + 2048 + tid * 4, l + 2048 + w * 256);   // floats [2048,4096)
}

#define BAR() do { __builtin_amdgcn_sched_barrier(0); \
                   __builtin_amdgcn_s_barrier();      \
                   __builtin_amdgcn_sched_barrier(0); } while (0)

// ---------------- prep: WsT[b][e][x] and Uh[b][y][e], both pre-scaled by CSC ----
// Grid 256 x (64,8). blk<128 -> Ws (16 x-rows/block), else Uh (16 y-rows/block).
// Wave w computes rows {2w, 2w+1}; thread: 2 rows x 4 cols -> 8 FMA per M float4.
__global__ __launch_bounds__(512) void prep_kernel(
    const float* __restrict__ enc, const float* __restrict__ dec,
    const float* __restrict__ Wa, const float* __restrict__ Ua,
    float* __restrict__ WsT, float* __restrict__ Uh)
{
    const int tx = threadIdx.x;           // 0..63
    const int w  = threadIdx.y;           // 0..7
    const int tid = w * 64 + tx;
    int blk = blockIdx.x;
    const bool isU = blk >= 128;
    if (isU) blk -= 128;
    const int b  = blk >> 4;              // 0..7
    const int r0 = (blk & 15) * 16;       // 16 rows per block

    __shared__ float rowsL[16 * NE];      // 16 KB input rows
    __shared__ float tL[16][260];         // transpose buffer (Ws only); stride 260 keeps
                                          // float4 row stores 16B-aligned, gathers 2-way max

    const float* src = (isU ? dec : enc) + ((size_t)b * 256 + r0) * NE;
    ((float4*)rowsL)[tid]       = ((const float4*)src)[tid];
    ((float4*)rowsL)[tid + 512] = ((const float4*)src)[tid + 512];
    __syncthreads();

    const float* M = isU ? Ua : Wa;
    const int e0 = tx * 4;
    const int rA = w * 2, rB = w * 2 + 1;
    float4 acc0 = make_float4(0.f, 0.f, 0.f, 0.f);
    float4 acc1 = make_float4(0.f, 0.f, 0.f, 0.f);
    const float* rowA = rowsL + rA * NE;
    const float* rowB = rowsL + rB * NE;

    for (int k = 0; k < NE; k += 8) {
        float4 mw[8];
        #pragma unroll
        for (int j = 0; j < 8; ++j)
            mw[j] = *(const float4*)(M + (size_t)(k + j) * NE + e0);
        #pragma unroll
        for (int j = 0; j < 8; ++j) {
            const float a = rowA[k + j];
            const float c = rowB[k + j];
            acc0.x = __builtin_fmaf(a, mw[j].x, acc0.x);
            acc0.y = __builtin_fmaf(a, mw[j].y, acc0.y);
            acc0.z = __builtin_fmaf(a, mw[j].z, acc0.z);
            acc0.w = __builtin_fmaf(a, mw[j].w, acc0.w);
            acc1.x = __builtin_fmaf(c, mw[j].x, acc1.x);
            acc1.y = __builtin_fmaf(c, mw[j].y, acc1.y);
            acc1.z = __builtin_fmaf(c, mw[j].z, acc1.z);
            acc1.w = __builtin_fmaf(c, mw[j].w, acc1.w);
        }
    }
    acc0.x *= CSC; acc0.y *= CSC; acc0.z *= CSC; acc0.w *= CSC;
    acc1.x *= CSC; acc1.y *= CSC; acc1.z *= CSC; acc1.w *= CSC;

    if (isU) {
        *(float4*)(Uh + ((size_t)b * TY + r0 + rA) * NE + e0) = acc0;
        *(float4*)(Uh + ((size_t)b * TY + r0 + rB) * NE + e0) = acc1;
    } else {
        *(float4*)&tL[rA][e0] = acc0;
        *(float4*)&tL[rB][e0] = acc1;
        __syncthreads();
        // transposed store: 1024 float4s (256 e x 4 xq), 2 per thread
        #pragma unroll
        for (int rep = 0; rep < 2; ++rep) {
            const int f4id = tid + rep * 512;
            const int e  = f4id >> 2;
            const int xq = (f4id & 3) * 4;
            float4 o;
            o.x = tL[xq + 0][e];
            o.y = tL[xq + 1][e];
            o.z = tL[xq + 2][e];
            o.w = tL[xq + 3][e];
            *(float4*)(WsT + (size_t)b * NE * TX + (size_t)e * TX + r0 + xq) = o;
        }
    }
}

// ---------------- attn: scores -> softmax -> context ----------------
// Grid 512 = (b, y-tile of 4). Block (64,8): wave w = (yl = w>>1, xh = w&1).
// Score: wave covers y=y0+yl, x in [xh*128, xh*128+128) (2 x's/lane), ALL e;
//   WsT[b] staged through 2x16KB LDS chunks (16 e-rows each), counted-vmcnt dbuf.
// Context: enc[b] staged the same way (16 x-rows/chunk); wave takes x-parity xl%2==xh,
//   lane owns e-quad tx*4; partials combined across xh via LDS.
__global__ __launch_bounds__(512) void attn_kernel(
    const float* __restrict__ enc, const float* __restrict__ WsT,
    const float* __restrict__ Uh, const float* __restrict__ Va,
    float* __restrict__ c_out, float* __restrict__ e_out)
{
    const int tx = threadIdx.x;            // 0..63
    const int w  = threadIdx.y;            // 0..7
    const int tid = w * 64 + tx;
    const int yl = w >> 1;                 // 0..3
    const int xh = w & 1;                  // 0..1
    const int b  = blockIdx.x >> 6;        // 0..7
    const int y0 = (blockIdx.x & 63) * 4;
    const int y  = y0 + yl;

    __shared__ float  wsbuf[2 * 4096];     // 32 KB chunk double-buffer
    __shared__ float2 uvL[4][NE];          // 8 KB: (uh'[y][e], v[e])
    __shared__ float  pL[4][TX];           // 4 KB
    __shared__ float  redM[4][2];
    __shared__ float  redS[4][2];

    const float* wsrc = WsT + (size_t)b * NE * TX;
    const float* esrc = enc + (size_t)b * TX * NE;

    // issue first score chunk, then stage (uh,v) while DMA flies
    stage_chunk(wsrc, wsbuf, tid, w);
    #pragma unroll
    for (int i = tid; i < 4 * NE; i += 512) {
        const int yy = i >> 8;
        const int e  = i & 255;
        uvL[yy][e] = make_float2(Uh[((size_t)b * TY + y0 + yy) * NE + e], Va[e]);
    }
    __syncthreads();   // drains vmcnt(0)+lgkmcnt(0): chunk0 + uv writes ready

    // ---- score: 16 chunks of 16 e-rows ----
    const int xp = xh * 128 + tx * 2;
    float2 acc = make_float2(0.f, 0.f);
    for (int c = 0; c < 16; ++c) {
        if (c + 1 < 16) {
            stage_chunk(wsrc + (c + 1) * 4096, wsbuf + ((c + 1) & 1) * 4096, tid, w);
            asm volatile("s_waitcnt vmcnt(2)" ::: "memory");
        } else {
            asm volatile("s_waitcnt vmcnt(0)" ::: "memory");
        }
        BAR();
        const float* bp = wsbuf + (c & 1) * 4096 + xp;
        const float2* uvp = &uvL[yl][c * 16];
        #pragma unroll
        for (int el = 0; el < 16; ++el) {
            const float2 ws2 = *(const float2*)(bp + el * 256);
            const float2 uv  = uvp[el];
            const float r0 = __builtin_amdgcn_rcpf(1.f + __builtin_amdgcn_exp2f(ws2.x + uv.x));
            const float r1 = __builtin_amdgcn_rcpf(1.f + __builtin_amdgcn_exp2f(ws2.y + uv.x));
            acc.x = __builtin_fmaf(uv.y, r0, acc.x);
            acc.y = __builtin_fmaf(uv.y, r1, acc.y);
        }
        BAR();
    }

    // ---- softmax over x (wave covers 128 x's; combine across the 2 xh waves) ----
    const float sx = -2.f * acc.x, sy = -2.f * acc.y;
    float m = fmaxf(sx, sy);
    #pragma unroll
    for (int off = 32; off; off >>= 1) m = fmaxf(m, __shfl_xor(m, off));
    if (tx == 0) redM[yl][xh] = m;
    __syncthreads();
    m = fmaxf(redM[yl][0], redM[yl][1]);
    float px = __expf(sx - m), py = __expf(sy - m);
    float sum = px + py;
    #pragma unroll
    for (int off = 32; off; off >>= 1) sum += __shfl_xor(sum, off);
    if (tx == 0) redS[yl][xh] = sum;
    __syncthreads();
    const float inv = __builtin_amdgcn_rcpf(redS[yl][0] + redS[yl][1]);
    px *= inv; py *= inv;
    *(float2*)(e_out + ((size_t)b * TY + y) * TX + xp) = make_float2(px, py);
    *(float2*)&pL[yl][xp] = make_float2(px, py);
    __syncthreads();   // pL visible to both xh waves; drains e_out stores

    // ---- context: 16 chunks of 16 x-rows; wave takes xl parity == xh ----
    stage_chunk(esrc, wsbuf, tid, w);
    float4 cacc = make_float4(0.f, 0.f, 0.f, 0.f);
    const int e4 = tx * 4;
    for (int c = 0; c < 16; ++c) {
        if (c + 1 < 16) {
            stage_chunk(esrc + (c + 1) * 4096, wsbuf + ((c + 1) & 1) * 4096, tid, w);
            asm volatile("s_waitcnt vmcnt(2)" ::: "memory");
        } else {
            asm volatile("s_waitcnt vmcnt(0)" ::: "memory");
        }
        BAR();
        const float* bp = wsbuf + (c & 1) * 4096 + e4;
        const float* prow = &pL[yl][c * 16];
        #pragma unroll
        for (int xl = xh; xl < 16; xl += 2) {
            const float4 ev = *(const float4*)(bp + xl * 256);
            const float pv = prow[xl];
            cacc.x = __builtin_fmaf(pv, ev.x, cacc.x);
            cacc.y = __builtin_fmaf(pv, ev.y, cacc.y);
            cacc.z = __builtin_fmaf(pv, ev.z, cacc.z);
            cacc.w = __builtin_fmaf(pv, ev.w, cacc.w);
        }
        BAR();
    }

    // combine xh partials (alias first 8 KB of wsbuf; chunk 15 used buf1)
    float4* accP = (float4*)wsbuf;
    accP[(xh * 4 + yl) * 64 + tx] = cacc;
    __syncthreads();
    if (xh == 0) {
        const float4 c0 = accP[(0 + yl) * 64 + tx];
        const float4 c1 = accP[(4 + yl) * 64 + tx];
        float4 cs;
        cs.x = c0.x + c1.x;
        cs.y = c0.y + c1.y;
        cs.z = c0.z + c1.z;
        cs.w = c0.w + c1.w;
        *(float4*)(c_out + ((size_t)b * TY + y) * NE + e4) = cs;
    }
}

extern "C" void kernel_launch(void* const* d_in, const int* in_sizes, int n_in,
                              void* d_out, int out_size, void* d_ws, size_t ws_size,
                              hipStream_t stream) {
    const float* enc = (const float*)d_in[0];   // [B,Tx,E]
    const float* dec = (const float*)d_in[1];   // [B,Ty,D]
    const float* Wa  = (const float*)d_in[2];   // [E,E]
    const float* Ua  = (const float*)d_in[3];   // [D,E]
    const float* Va  = (const float*)d_in[4];   // [E,1]

    float* c_out = (float*)d_out;                               // [B,Ty,E]
    float* e_out = (float*)d_out + (size_t)NB * TY * NE;        // [B,Ty,Tx]

    float* WsT = (float*)d_ws;                                  // [B][E][Tx]
    float* Uh  = (float*)d_ws + (size_t)NB * NE * TX;           // [B][Ty][E]

    prep_kernel<<<256, dim3(64, 8), 0, stream>>>(enc, dec, Wa, Ua, WsT, Uh);
    attn_kernel<<<512, dim3(64, 8), 0, stream>>>(enc, WsT, Uh, Va, c_out, e_out);
}